// Round 5
// baseline (1194.862 us; speedup 1.0000x reference)
//
#include <hip/hip_runtime.h>

// FlowNetC correlation, MI355X/gfx950. fp32 in/out, f16 MFMA (f32 accum).
// B=8 C=256 H=64 W=96; 21x21 displacements step 2, pad 20, scale 1/C.
//
// R4: block = (b, 4 y-rows, 2 dy) -> acc 72 regs, LDS 42 KB, 3 blocks/CU
//     (was 1 -> latency exposed, MfmaUtil 5.5%). Grid 1408 = 8 XCD x 176.
//     ebuf stride 97 (was 96 == 0 mod 32 -> 11-way epilogue bank conflict,
//     the 1.63e7 SQ_LDS_BANK_CONFLICT source).
// Main-loop LDS scheme unchanged from R3 (verified correct + bank-clean):
//     rows of 32B (16 f16 = 16 k), PHYS low-3-bit rotate, chunk XOR swizzle,
//     applied identically on write and read.

#define ND 21
#define CIN 6144           // 64*96
#define BIN 1572864        // 256*64*96
#define BOUT (441 * 6144)

typedef _Float16 f16;
typedef _Float16 f16x4 __attribute__((ext_vector_type(4)));
typedef _Float16 f16x8 __attribute__((ext_vector_type(8)));
typedef float    f32x4 __attribute__((ext_vector_type(4)));

// LDS rows (32B = 16 k). Logical row R -> physical PHYS(R) (rotate low 3 bits).
// data(R,k) at f16-index P*16 + chunk*8 + (k&7), chunk = (k>>3) ^ ((P>>2)&1).
// s1 rows 0..383:   R = (y*2+par)*48 + x'           (x' 0..47)
// s2 rows 384..1343: R = 384 + (r*2+par)*80 + w'    (w' 0..79; 0..9 & 58..79 pad)
#define S2R0 384
#define NROWS 1344   // 1344*32 = 43008 B

__device__ __forceinline__ int PHYS(int R) {
    return ((R >> 1) & 3) | ((R & 1) << 2) | (R & ~7);
}

__global__ __launch_bounds__(512, 6) void corr_kernel(const float* __restrict__ in1,
                                                      const float* __restrict__ in2,
                                                      float* __restrict__ out) {
    __shared__ __align__(16) unsigned char smem[NROWS * 32];
    f16*   S    = (f16*)smem;
    float* ebuf = (float*)smem;   // epilogue reuse: 8 regions x 11 x 97 f32 = 34144 B

    const int tid = threadIdx.x;
    // XCD-bijective swizzle: 1408 = 8 XCDs x 176; each XCD owns one batch b.
    const int bid = (blockIdx.x & 7) * 176 + (blockIdx.x >> 3);
    const int b   = bid / 176;
    const int rem0 = bid % 176;
    const int yt  = rem0 / 11;    // y-tile (0..15)
    const int iyt = rem0 % 11;    // dy-tile (0..10), dy = iyt*2 + dyg
    const int y0       = yt * 4;
    const int row_base = y0 + 4 * iyt - 20;   // in2 global row for local r: row_base + r

    const int wid  = tid >> 6;
    const int lane = tid & 63;
    const int y_l  = wid & 3;
    const int dyg  = wid >> 2;     // 0..1
    const int g    = lane >> 4;    // 0..3
    const int c16  = lane & 15;
    const int iy   = iyt * 2 + dyg;
    const bool wave_active = iy < ND;

    // zero all LDS once (covers s2 pad slots which staging never rewrites)
    for (int u = tid; u < NROWS * 8; u += 512) ((int*)smem)[u] = 0;

    f32x4 acc[2][3][3];   // [par][mt][d]
    const f32x4 z4 = {0.f, 0.f, 0.f, 0.f};
#pragma unroll
    for (int p = 0; p < 2; ++p)
#pragma unroll
        for (int mt = 0; mt < 3; ++mt)
#pragma unroll
            for (int d = 0; d < 3; ++d) acc[p][mt][d] = z4;

    const float* in1b = in1 + (size_t)b * BIN + y0 * 96;
    const float* in2b = in2 + (size_t)b * BIN;

    for (int ch = 0; ch < 16; ++ch) {
        const int c0 = ch * 16;
        __syncthreads();   // prev compute done before overwrite (also orders zero-init)

        // ---- staging: 480 tasks (1 pass). task = (rows-quad, k-half):
        // 8 coalesced float4 loads across k -> register transpose -> 4 ds_write_b128.
        if (tid < 480) {
            const int task = tid;
            int x4, kh, rowbase, ps;
            const float* gp;
            bool valid;
            if (task < 192) {                      // in1: (y, x4, kh)
                const int y = task / 48, rem = task % 48;
                x4 = rem >> 1; kh = rem & 1;
                gp = in1b + y * 96 + x4 * 4;
                rowbase = y * 96 + 2 * x4;         // (y*2+0)*48 + 2*x4
                ps = 48; valid = true;
            } else {                               // in2: (r, x4, kh), r in 0..5
                const int t2 = task - 192;
                const int r = t2 / 48, rem = t2 % 48;
                x4 = rem >> 1; kh = rem & 1;
                const int gy = row_base + r;
                valid = (gy >= 0) && (gy < 64);
                const int gyc = valid ? gy : 0;
                gp = in2b + gyc * 96 + x4 * 4;
                rowbase = S2R0 + r * 160 + 10 + 2 * x4;   // + par*80 + dx
                ps = 80;
            }
            float4 v[8];
#pragma unroll
            for (int j = 0; j < 8; ++j) {
                if (valid) v[j] = *(const float4*)(gp + (c0 + kh * 8 + j) * CIN);
                else       v[j] = make_float4(0.f, 0.f, 0.f, 0.f);
            }
            f16x8 rv[4];   // rv[i]: i = par + 2*dx
#pragma unroll
            for (int j = 0; j < 8; ++j) {
                rv[0][j] = (f16)v[j].x; rv[1][j] = (f16)v[j].y;
                rv[2][j] = (f16)v[j].z; rv[3][j] = (f16)v[j].w;
            }
#pragma unroll
            for (int i = 0; i < 4; ++i) {
                const int P = PHYS(rowbase + (i & 1) * ps + (i >> 1));
                *(f16x8*)&S[P * 16 + ((kh ^ ((P >> 2) & 1)) << 3)] = rv[i];
            }
        }
        __syncthreads();

        // ---- compute: frags via single ds_read_b64 each (perm+swizzled) ----
        if (wave_active) {
#pragma unroll
            for (int par = 0; par < 2; ++par) {
                f16x4 a[3];
#pragma unroll
                for (int mt = 0; mt < 3; ++mt) {
                    const int P = PHYS((y_l * 2 + par) * 48 + mt * 16 + c16);
                    a[mt] = *(const f16x4*)&S[P * 16 + (((g >> 1) ^ ((P >> 2) & 1)) << 3) +
                                              ((g & 1) << 2)];
                }
                const int r = y_l + 2 * dyg;
                f16x4 bf[5];
#pragma unroll
                for (int wt = 0; wt < 5; ++wt) {
                    const int P = PHYS(S2R0 + (r * 2 + par) * 80 + wt * 16 + c16);
                    bf[wt] = *(const f16x4*)&S[P * 16 + (((g >> 1) ^ ((P >> 2) & 1)) << 3) +
                                               ((g & 1) << 2)];
                }
#pragma unroll
                for (int mt = 0; mt < 3; ++mt)
#pragma unroll
                    for (int d = 0; d < 3; ++d)
                        acc[par][mt][d] = __builtin_amdgcn_mfma_f32_16x16x16f16(
                            a[mt], bf[mt + d], acc[par][mt][d], 0, 0, 0);
            }
        }
    }

    // ---- epilogue: diag-extract via LDS (stride 97, conflict-free), coalesced stores ----
    __syncthreads();
    const float scale = 1.0f / 256.0f;
#pragma unroll
    for (int q = 0; q < 2; ++q) {
        const int j0 = q * 11;
        const int nj = q ? 10 : 11;
        if (wave_active) {
#pragma unroll
            for (int par = 0; par < 2; ++par)
#pragma unroll
                for (int mt = 0; mt < 3; ++mt)
#pragma unroll
                    for (int d = 0; d < 3; ++d)
#pragma unroll
                        for (int rg = 0; rg < 4; ++rg) {
                            const int xq = mt * 16 + 4 * g + rg;       // x'
                            const int j  = (mt + d) * 16 + c16 - xq;   // w' - x'
                            if (j >= j0 && j < j0 + nj)
                                ebuf[wid * 1067 + (j - j0) * 97 + 2 * xq + par] =
                                    acc[par][mt][d][rg] * scale;
                        }
        }
        __syncthreads();
        const int total = 8 * nj * 96;
        for (int u = tid; u < total; u += 512) {
            const int rgn  = u / (nj * 96);
            const int rem  = u % (nj * 96);
            const int jj   = rem / 96;
            const int x    = rem % 96;
            const int vy_l = rgn & 3;
            const int viy  = iyt * 2 + (rgn >> 2);
            if (viy < ND)
                out[(size_t)b * BOUT + (viy * ND + j0 + jj) * CIN +
                    (y0 + vy_l) * 96 + x] = ebuf[rgn * 1067 + jj * 97 + x];
        }
        __syncthreads();
    }
}

extern "C" void kernel_launch(void* const* d_in, const int* in_sizes, int n_in,
                              void* d_out, int out_size, void* d_ws, size_t ws_size,
                              hipStream_t stream) {
    const float* in1 = (const float*)d_in[0];
    const float* in2 = (const float*)d_in[1];
    float* out = (float*)d_out;
    corr_kernel<<<1408, 512, 0, stream>>>(in1, in2, out);
}

// Round 7
// 330.026 us; speedup vs baseline: 3.6205x; 3.6205x over previous
//
#include <hip/hip_runtime.h>

// FlowNetC correlation, MI355X/gfx950. fp32 in/out, f16 MFMA (f32 accum).
// B=8 C=256 H=64 W=96; 21x21 displacements step 2, pad 20, scale 1/C.
//
// R7: block = (b, 4y, 2dy) @ 1024 thr / 16 waves; wave = (y_l, dy_l, PAR)
//     -> acc 36 VGPR/thread; peak liveness ~110 <= 128 cap of (1024,4)
//     (R6 draft needed ~140 -> would spill like R5 did).
//     Double-buffered LDS 2x43008 B, issue-early staging (T14): loads(t+1)
//     -> compute(t) -> cvt+write(t+1) -> ONE barrier per chunk.
//     Frag LDS offsets precomputed (chunk-invariant). Grid 1408 = 8 XCD x 176;
//     176 blocks = one full batch per XCD (L2/L3 locality).
// LDS scheme identical to R4-verified: 32B rows (16 k f16), PHYS low-3
// rotate, chunk-XOR swizzle, applied identically on write and read.

#define ND 21
#define CIN 6144           // 64*96
#define BIN 1572864        // 256*64*96
#define BOUT (441 * 6144)
#define S2R0 384
#define NROWS 1344              // 384 s1 rows + 960 s2 rows
#define BUF (NROWS * 32)        // 43008 B per buffer
#define SMEM_TOTAL (2 * BUF)    // 86016 B dynamic LDS

typedef _Float16 f16;
typedef _Float16 f16x4 __attribute__((ext_vector_type(4)));
typedef _Float16 f16x8 __attribute__((ext_vector_type(8)));
typedef float    f32x4 __attribute__((ext_vector_type(4)));

__device__ __forceinline__ int PHYS(int R) {
    return ((R >> 1) & 3) | ((R & 1) << 2) | (R & ~7);
}
// byte offset of the (16k-row R, k-group g) fragment, swizzle included
__device__ __forceinline__ int FRAGOFF(int R, int g) {
    const int P = PHYS(R);
    return 2 * (P * 16 + (((g >> 1) ^ ((P >> 2) & 1)) << 3) + ((g & 1) << 2));
}

__global__ __launch_bounds__(1024, 4) void corr_kernel(const float* __restrict__ in1,
                                                       const float* __restrict__ in2,
                                                       float* __restrict__ out) {
    extern __shared__ __align__(16) unsigned char smem[];

    const int tid = threadIdx.x;
    // XCD swizzle: 1408 = 8 XCDs x 176; each XCD owns exactly one batch b.
    const int bid  = (blockIdx.x & 7) * 176 + (blockIdx.x >> 3);
    const int b    = bid / 176;
    const int rem0 = bid % 176;
    const int yt   = rem0 / 11;    // y-tile 0..15
    const int iyt  = rem0 % 11;    // dy-tile 0..10 (dy = 2*iyt + dy_l)
    const int y0       = yt * 4;
    const int row_base = y0 + 4 * iyt - 20;   // in2 row for local r: row_base + r

    const int wid  = tid >> 6;        // 0..15
    const int lane = tid & 63;
    const int par  = wid & 1;
    const int y_l  = (wid >> 1) & 3;
    const int dy_l = wid >> 3;        // 0..1
    const int g    = lane >> 4;
    const int c16  = lane & 15;
    const int iy   = iyt * 2 + dy_l;
    const bool wave_active = iy < ND;
    const int r_w  = y_l + 2 * dy_l;  // in2 local row 0..5

    // chunk-invariant fragment offsets (within a buffer)
    int aoff[3], boff[5];
#pragma unroll
    for (int mt = 0; mt < 3; ++mt)
        aoff[mt] = FRAGOFF((y_l * 2 + par) * 48 + mt * 16 + c16, g);
#pragma unroll
    for (int wt = 0; wt < 5; ++wt)
        boff[wt] = FRAGOFF(S2R0 + (r_w * 2 + par) * 80 + wt * 16 + c16, g);

    // ---- stager setup (tid < 480): chunk-invariant addresses/offsets ----
    const bool is_stager = tid < 480;
    const float* gp0 = in1;
    bool valid = false;
    int wboff[4] = {0, 0, 0, 0};
    if (is_stager) {
        int x4, kh, rowbase, ps;
        if (tid < 192) {                          // in1: (y 0..3, x4 0..23, kh 0..1)
            const int y = tid / 48, rem = tid % 48;
            x4 = rem >> 1; kh = rem & 1;
            gp0 = in1 + (size_t)b * BIN + (y0 + y) * 96 + x4 * 4;
            rowbase = y * 96 + 2 * x4; ps = 48; valid = true;
        } else {                                  // in2: (r 0..5, x4, kh)
            const int t2 = tid - 192;
            const int r = t2 / 48, rem = t2 % 48;
            x4 = rem >> 1; kh = rem & 1;
            const int gy = row_base + r;
            valid = (gy >= 0) && (gy < 64);
            gp0 = in2 + (size_t)b * BIN + (valid ? gy : 0) * 96 + x4 * 4;
            rowbase = S2R0 + r * 160 + 10 + 2 * x4; ps = 80;
        }
        gp0 += kh * 8 * CIN;                      // fold k-half into base
#pragma unroll
        for (int i = 0; i < 4; ++i) {             // i = par + 2*dx
            const int P = PHYS(rowbase + (i & 1) * ps + (i >> 1));
            wboff[i] = 2 * (P * 16 + ((kh ^ ((P >> 2) & 1)) << 3));
        }
    }

    // zero both buffers once (pad w'-slots are never rewritten)
    for (int u = tid; u < SMEM_TOTAL / 4; u += 1024) ((int*)smem)[u] = 0;

    f32x4 acc[3][3];   // [mt][d] — ONE parity per wave
    const f32x4 z4 = {0.f, 0.f, 0.f, 0.f};
#pragma unroll
    for (int mt = 0; mt < 3; ++mt)
#pragma unroll
        for (int d = 0; d < 3; ++d) acc[mt][d] = z4;

    __syncthreads();

    // ---- prologue: stage chunk 0 into buffer 0 ----
    if (is_stager) {
        float4 v[8];
#pragma unroll
        for (int j = 0; j < 8; ++j)
            v[j] = valid ? *(const float4*)(gp0 + j * CIN) : make_float4(0.f, 0.f, 0.f, 0.f);
        f16x8 rv[4];
#pragma unroll
        for (int j = 0; j < 8; ++j) {
            rv[0][j] = (f16)v[j].x; rv[1][j] = (f16)v[j].y;
            rv[2][j] = (f16)v[j].z; rv[3][j] = (f16)v[j].w;
        }
#pragma unroll
        for (int i = 0; i < 4; ++i) *(f16x8*)(smem + wboff[i]) = rv[i];
    }
    __syncthreads();

    // ---- main loop: issue loads(t+1) -> compute(t) -> write(t+1) -> barrier ----
    int cur = 0;
    for (int ch = 0; ch < 16; ++ch) {
        float4 v[8];
        const bool pf = is_stager && (ch < 15);
        if (pf) {
            const float* gp = gp0 + (ch + 1) * 16 * CIN;
#pragma unroll
            for (int j = 0; j < 8; ++j)
                v[j] = valid ? *(const float4*)(gp + j * CIN) : make_float4(0.f, 0.f, 0.f, 0.f);
        }
        if (wave_active) {
            const unsigned char* Sb = smem + cur * BUF;
            f16x4 a[3];
#pragma unroll
            for (int mt = 0; mt < 3; ++mt) a[mt] = *(const f16x4*)(Sb + aoff[mt]);
            f16x4 bf[5];
#pragma unroll
            for (int wt = 0; wt < 5; ++wt) bf[wt] = *(const f16x4*)(Sb + boff[wt]);
#pragma unroll
            for (int mt = 0; mt < 3; ++mt)
#pragma unroll
                for (int d = 0; d < 3; ++d)
                    acc[mt][d] = __builtin_amdgcn_mfma_f32_16x16x16f16(
                        a[mt], bf[mt + d], acc[mt][d], 0, 0, 0);
        }
        if (pf) {   // write chunk ch+1 into the buffer nobody reads this chunk
            unsigned char* Sw = smem + (cur ^ 1) * BUF;
            f16x8 rv[4];
#pragma unroll
            for (int j = 0; j < 8; ++j) {
                rv[0][j] = (f16)v[j].x; rv[1][j] = (f16)v[j].y;
                rv[2][j] = (f16)v[j].z; rv[3][j] = (f16)v[j].w;
            }
#pragma unroll
            for (int i = 0; i < 4; ++i) *(f16x8*)(Sw + wboff[i]) = rv[i];
        }
        __syncthreads();
        cur ^= 1;
    }

    // ---- epilogue: 8 plane-regions, par-waves share a region; 2 j-groups ----
    float* ebuf = (float*)smem;
    const float scale = 1.0f / 256.0f;
#pragma unroll
    for (int q = 0; q < 2; ++q) {
        const int j0 = q * 11;
        const int nj = q ? 10 : 11;
        if (wave_active) {
            const int rgn = wid >> 1;   // plane = dy_l*4 + y_l
#pragma unroll
            for (int mt = 0; mt < 3; ++mt)
#pragma unroll
                for (int d = 0; d < 3; ++d)
#pragma unroll
                    for (int rg = 0; rg < 4; ++rg) {
                        const int xq = mt * 16 + 4 * g + rg;       // x'
                        const int j  = (mt + d) * 16 + c16 - xq;   // w' - x'
                        if (j >= j0 && j < j0 + nj)
                            ebuf[rgn * 1067 + (j - j0) * 97 + 2 * xq + par] =
                                acc[mt][d][rg] * scale;
                    }
        }
        __syncthreads();
        const int total = 8 * nj * 96;
        for (int u = tid; u < total; u += 1024) {
            const int rgn = u / (nj * 96);
            const int rem = u % (nj * 96);
            const int jj  = rem / 96;
            const int x   = rem % 96;
            const int vy_l = rgn & 3;
            const int viy  = iyt * 2 + (rgn >> 2);
            if (viy < ND)
                out[(size_t)b * BOUT + (viy * ND + j0 + jj) * CIN +
                    (y0 + vy_l) * 96 + x] = ebuf[rgn * 1067 + jj * 97 + x];
        }
        __syncthreads();
    }
}

extern "C" void kernel_launch(void* const* d_in, const int* in_sizes, int n_in,
                              void* d_out, int out_size, void* d_ws, size_t ws_size,
                              hipStream_t stream) {
    const float* in1 = (const float*)d_in[0];
    const float* in2 = (const float*)d_in[1];
    float* out = (float*)d_out;
    (void)hipFuncSetAttribute((const void*)corr_kernel,
                              hipFuncAttributeMaxDynamicSharedMemorySize, SMEM_TOTAL);
    corr_kernel<<<1408, 1024, SMEM_TOTAL, stream>>>(in1, in2, out);
}